// Round 1
// baseline (1275.371 us; speedup 1.0000x reference)
//
#include <hip/hip_runtime.h>

// Problem constants
constexpr int S = 8, B = 128, T = 256, N = 128;
constexpr int L = 64, Hh = 128, Hd = 64, Hl = 128;

#define DEVFN __device__ __forceinline__

DEVFN float softplus_f(float x) {
    // stable log(1+e^x)
    return (x > 0.f) ? (x + log1pf(expf(-x))) : log1pf(expf(x));
}

// ---------------------------------------------------------------------------
// Kernel A: per (b,t) row:  h = tanh(y @ W_be + b_be);  A = h @ W1a + b_le1
// W1a = first 128 rows of W_le1. Also stash h at t==0 into h0.
// grid: 2048 blocks x 256 threads, 16 rows per block.
// ---------------------------------------------------------------------------
__global__ __launch_bounds__(256) void kA(
        const float* __restrict__ y,
        const float* __restrict__ W_be, const float* __restrict__ b_be,
        const float* __restrict__ W_le1, const float* __restrict__ b_le1,
        float* __restrict__ A, float* __restrict__ h0) {
    __shared__ float Wb[128 * 128];   // 64KB
    __shared__ float Wa[128 * 128];   // 64KB
    __shared__ float yt[128][16];     // 8KB  (transposed [n][row])
    __shared__ float ht[128][16];     // 8KB
    __shared__ float bbe[128], ble1[128];

    const int tid = threadIdx.x;
    {
        const float4* s1 = (const float4*)W_be;
        const float4* s2 = (const float4*)W_le1;   // rows 0..127 = W1a
        float4* d1 = (float4*)Wb;
        float4* d2 = (float4*)Wa;
        for (int i = tid; i < 4096; i += 256) { d1[i] = s1[i]; d2[i] = s2[i]; }
    }
    if (tid < 128) { bbe[tid] = b_be[tid]; ble1[tid] = b_le1[tid]; }

    const int bt0 = blockIdx.x * 16;
    {
        const float4* ys = (const float4*)(y + (size_t)bt0 * 128);
        for (int q = tid; q < 512; q += 256) {
            float4 v = ys[q];
            int r = q >> 5, n4 = (q & 31) * 4;
            yt[n4 + 0][r] = v.x; yt[n4 + 1][r] = v.y;
            yt[n4 + 2][r] = v.z; yt[n4 + 3][r] = v.w;
        }
    }
    __syncthreads();

    const int j = tid & 127, rh = tid >> 7;  // 8 rows each
    float acc[8];

    // h GEMM
    #pragma unroll
    for (int s = 0; s < 8; s++) acc[s] = bbe[j];
    #pragma unroll 4
    for (int k = 0; k < 128; k++) {
        float w = Wb[k * 128 + j];
        float4 a0 = *(const float4*)&yt[k][rh * 8];
        float4 a1 = *(const float4*)&yt[k][rh * 8 + 4];
        acc[0] += w * a0.x; acc[1] += w * a0.y; acc[2] += w * a0.z; acc[3] += w * a0.w;
        acc[4] += w * a1.x; acc[5] += w * a1.y; acc[6] += w * a1.z; acc[7] += w * a1.w;
    }
    #pragma unroll
    for (int s = 0; s < 8; s++) ht[j][rh * 8 + s] = tanhf(acc[s]);
    __syncthreads();

    // A GEMM
    #pragma unroll
    for (int s = 0; s < 8; s++) acc[s] = ble1[j];
    #pragma unroll 4
    for (int k = 0; k < 128; k++) {
        float w = Wa[k * 128 + j];
        float4 a0 = *(const float4*)&ht[k][rh * 8];
        float4 a1 = *(const float4*)&ht[k][rh * 8 + 4];
        acc[0] += w * a0.x; acc[1] += w * a0.y; acc[2] += w * a0.z; acc[3] += w * a0.w;
        acc[4] += w * a1.x; acc[5] += w * a1.y; acc[6] += w * a1.z; acc[7] += w * a1.w;
    }
    #pragma unroll
    for (int s = 0; s < 8; s++) {
        int r = rh * 8 + s;
        A[(size_t)(bt0 + r) * 128 + j] = acc[s];
    }
    if (rh == 0 && (bt0 & 255) == 0) {
        h0[(bt0 >> 8) * 128 + j] = ht[j][0];
    }
}

// ---------------------------------------------------------------------------
// Kernel B: initial step. One block per b (128 threads).
// mp0 = h0[b] @ W_ic + b_ic; m=mp0[:64]; P=softplus(mp0[64:]);
// z0[s,b,:] = m + sqrt(P)*eps0; kl0 -> klp[0][b][0]; klp[1][b][0]=0.
// ---------------------------------------------------------------------------
__global__ __launch_bounds__(128) void kB(
        const float* __restrict__ h0, const float* __restrict__ W_ic,
        const float* __restrict__ b_ic, const float* __restrict__ m_0,
        const float* __restrict__ log_Q_0, const float* __restrict__ eps0,
        float* __restrict__ zout, float* __restrict__ klp) {
    __shared__ float hr[128];
    __shared__ float mp[128];
    const int b = blockIdx.x, tid = threadIdx.x;
    hr[tid] = h0[b * 128 + tid];
    __syncthreads();
    float acc = b_ic[tid];
    #pragma unroll 8
    for (int k = 0; k < 128; k++) acc += hr[k] * W_ic[k * 128 + tid];
    mp[tid] = acc;
    __syncthreads();

    float term = 0.f;
    if (tid < 64) {
        float m = mp[tid];
        float P = softplus_f(mp[tid + 64]);
        float sq = sqrtf(P);
        #pragma unroll
        for (int s = 0; s < 8; s++) {
            float e = eps0[((size_t)s * B + b) * 64 + tid];
            zout[(((size_t)s * B + b) * T + 0) * 64 + tid] = m + sq * e;
        }
        float Q0 = softplus_f(log_Q_0[tid]);
        float d = m - m_0[tid];
        term = 0.5f * (logf(Q0) - logf(P) + (P + d * d) / Q0 - 1.f);
    }
    #pragma unroll
    for (int off = 32; off; off >>= 1) term += __shfl_down(term, off);
    if (tid == 0) {
        klp[(size_t)b * T + 0] = term;             // kl0 (no sample mean)
        klp[(size_t)B * T + (size_t)b * T + 0] = 0.f;
    }
}

// ---------------------------------------------------------------------------
// Kernel C: the sequential scan, t = 1..T-1.
// 256 blocks: block -> (b = bid>>1, s-half = bid&1 -> 4 samples). 256 threads.
// All weights in LDS (fp32, 128KB). 5 barriers/step.
// ---------------------------------------------------------------------------
__global__ __launch_bounds__(256) void kC(
        const float* __restrict__ Aglob,
        const float* __restrict__ W_le1, const float* __restrict__ W_le2,
        const float* __restrict__ b_le2,
        const float* __restrict__ W_dyn1, const float* __restrict__ b_dyn1,
        const float* __restrict__ W_dyn2, const float* __restrict__ b_dyn2,
        const float* __restrict__ log_Q, const float* __restrict__ eps,
        float* __restrict__ zout, float* __restrict__ klp) {
    __shared__ float W1b[64 * 128];     // 32KB (rows 128..191 of W_le1)
    __shared__ float W2[128 * 128];     // 64KB
    __shared__ float Wd1[64 * 64];      // 16KB
    __shared__ float Wd2[64 * 64];      // 16KB
    __shared__ float zt[64][4];
    __shared__ float hid[128][4];
    __shared__ float gt[64][4];
    __shared__ float mpt[128][4];
    __shared__ float mut[64][4];
    __shared__ float part[2][128][4];
    __shared__ float part2[4][64][4];
    __shared__ float bb2[128], bd1[64], bd2[64];
    __shared__ float Qv[64], lQv[64];
    __shared__ float red4[4];

    const int tid = threadIdx.x;
    const int b = blockIdx.x >> 1, sh = blockIdx.x & 1, s0 = sh * 4;

    {
        const float4* s1 = (const float4*)(W_le1 + 128 * 128);
        float4* d1 = (float4*)W1b;
        for (int i = tid; i < 2048; i += 256) d1[i] = s1[i];
        const float4* s2 = (const float4*)W_le2;
        float4* d2 = (float4*)W2;
        for (int i = tid; i < 4096; i += 256) d2[i] = s2[i];
        const float4* s3 = (const float4*)W_dyn1;
        float4* d3 = (float4*)Wd1;
        for (int i = tid; i < 1024; i += 256) d3[i] = s3[i];
        const float4* s4 = (const float4*)W_dyn2;
        float4* d4 = (float4*)Wd2;
        for (int i = tid; i < 1024; i += 256) d4[i] = s4[i];
    }
    if (tid < 128) bb2[tid] = b_le2[tid];
    if (tid < 64) {
        bd1[tid] = b_dyn1[tid]; bd2[tid] = b_dyn2[tid];
        float q = softplus_f(log_Q[tid]);
        Qv[tid] = q; lQv[tid] = logf(q);
    }
    {   // stage z0
        int si = tid >> 6, l = tid & 63;
        zt[l][si] = zout[(((size_t)(s0 + si) * B + b) * T + 0) * 64 + l];
    }
    __syncthreads();

    const int j = tid & 127, kh = tid >> 7;     // GEMM mapping (L1/L2)
    const int l = tid & 63, si = tid >> 6;      // elementwise mapping
    const int j2 = tid & 63, kq = tid >> 6;     // dyn mapping
    const int wid = tid >> 6, lane = tid & 63;

    for (int t = 1; t < T; t++) {
        // prefetch this step's global data (consumed after barriers)
        float a_reg = Aglob[((size_t)b * T + t) * 128 + j];
        float e_reg = eps[((((size_t)(t - 1) * S) + (s0 + si)) * B + b) * 64 + l];

        // --- L1 partial: z_prev @ W1b (K split over kh) ---
        float4 acc = {0.f, 0.f, 0.f, 0.f};
        #pragma unroll 8
        for (int kk = 0; kk < 32; kk++) {
            int k = kh * 32 + kk;
            float w = W1b[k * 128 + j];
            float4 z4 = *(const float4*)&zt[k][0];
            acc.x += w * z4.x; acc.y += w * z4.y; acc.z += w * z4.z; acc.w += w * z4.w;
        }
        *(float4*)&part[kh][j][0] = acc;

        // --- dyn1 partial: tanh(z_prev @ Wd1 + bd1) stage (K split over kq) ---
        float4 accd = {0.f, 0.f, 0.f, 0.f};
        #pragma unroll 8
        for (int kk = 0; kk < 16; kk++) {
            int k = kq * 16 + kk;
            float w = Wd1[k * 64 + j2];
            float4 z4 = *(const float4*)&zt[k][0];
            accd.x += w * z4.x; accd.y += w * z4.y; accd.z += w * z4.z; accd.w += w * z4.w;
        }
        *(float4*)&part2[kq][j2][0] = accd;
        __syncthreads();   // (1)

        {   // L1 finalize -> hid ; dyn1 finalize -> gt
            int sp = 2 * kh;
            float4 p0 = *(const float4*)&part[0][j][0];
            float4 p1 = *(const float4*)&part[1][j][0];
            float v0 = (sp == 0 ? p0.x + p1.x : p0.z + p1.z) + a_reg;
            float v1 = (sp == 0 ? p0.y + p1.y : p0.w + p1.w) + a_reg;
            hid[j][sp] = tanhf(v0);
            hid[j][sp + 1] = tanhf(v1);

            float gv = bd1[j2];
            #pragma unroll
            for (int q = 0; q < 4; q++) gv += part2[q][j2][kq];
            gt[j2][kq] = tanhf(gv);
        }
        __syncthreads();   // (2)

        // --- L2 partial: hid @ W2 ---
        acc.x = acc.y = acc.z = acc.w = 0.f;
        #pragma unroll 8
        for (int kk = 0; kk < 64; kk++) {
            int k = kh * 64 + kk;
            float w = W2[k * 128 + j];
            float4 h4 = *(const float4*)&hid[k][0];
            acc.x += w * h4.x; acc.y += w * h4.y; acc.z += w * h4.z; acc.w += w * h4.w;
        }
        *(float4*)&part[kh][j][0] = acc;

        // --- dyn2 partial: gt @ Wd2 ---
        accd.x = accd.y = accd.z = accd.w = 0.f;
        #pragma unroll 8
        for (int kk = 0; kk < 16; kk++) {
            int k = kq * 16 + kk;
            float w = Wd2[k * 64 + j2];
            float4 g4 = *(const float4*)&gt[k][0];
            accd.x += w * g4.x; accd.y += w * g4.y; accd.z += w * g4.z; accd.w += w * g4.w;
        }
        *(float4*)&part2[kq][j2][0] = accd;
        __syncthreads();   // (3)

        {   // L2 finalize -> mpt ; dyn2 finalize -> mut
            int sp = 2 * kh;
            float4 p0 = *(const float4*)&part[0][j][0];
            float4 p1 = *(const float4*)&part[1][j][0];
            float bias = bb2[j];
            mpt[j][sp]     = (sp == 0 ? p0.x + p1.x : p0.z + p1.z) + bias;
            mpt[j][sp + 1] = (sp == 0 ? p0.y + p1.y : p0.w + p1.w) + bias;

            float mv = bd2[j2];
            #pragma unroll
            for (int q = 0; q < 4; q++) mv += part2[q][j2][kq];
            mut[j2][kq] = mv;
        }
        __syncthreads();   // (4)

        // --- z update + KL (thread (l, si)) ---
        float m = mpt[l][si];
        float P = softplus_f(mpt[l + 64][si]);
        float znew = m + sqrtf(P) * e_reg;
        zout[(((size_t)(s0 + si) * B + b) * T + t) * 64 + l] = znew;
        zt[l][si] = znew;
        float mu = mut[l][si];
        float d = m - mu;
        float term = 0.5f * (lQv[l] - logf(P) + (P + d * d) / Qv[l] - 1.f);
        #pragma unroll
        for (int off = 32; off; off >>= 1) term += __shfl_down(term, off);
        if (lane == 0) red4[wid] = term;
        __syncthreads();   // (5)
        if (tid == 0) {
            klp[(size_t)sh * B * T + (size_t)b * T + t] =
                0.125f * (red4[0] + red4[1] + red4[2] + red4[3]);
        }
    }
}

// ---------------------------------------------------------------------------
// Kernel P: projection + Poisson ell + m_stat. 4096 blocks x 256 threads,
// 8 (b,t) pairs per block. C (64x128) in LDS.
// ---------------------------------------------------------------------------
__global__ __launch_bounds__(256) void kP(
        const float* __restrict__ zin, const float* __restrict__ C,
        const float* __restrict__ b_c, const float* __restrict__ y,
        float* __restrict__ m_stat, float* __restrict__ ell) {
    __shared__ float Cl[64 * 128];   // 32KB
    __shared__ float bc[128];
    __shared__ float ztl[64][8];
    __shared__ float red4[4];

    const int tid = threadIdx.x;
    {
        const float4* s = (const float4*)C;
        float4* d = (float4*)Cl;
        for (int i = tid; i < 2048; i += 256) d[i] = s[i];
    }
    if (tid < 128) bc[tid] = b_c[tid];

    const int bt0 = blockIdx.x * 8;
    const int n = tid & 127, shh = tid >> 7;

    for (int it = 0; it < 8; it++) {
        const int bt = bt0 + it;
        const int b = bt >> 8, t = bt & 255;
        __syncthreads();   // protects ztl & red4 reuse (also covers Cl on it=0)
        {
            int s_ = tid >> 6, l_ = tid & 63;
            ztl[l_][s_] = zin[(((size_t)s_ * B + b) * T + t) * 64 + l_];
            int i1 = tid + 256;
            s_ = i1 >> 6; l_ = i1 & 63;
            ztl[l_][s_] = zin[(((size_t)s_ * B + b) * T + t) * 64 + l_];
        }
        __syncthreads();
        if (tid < 64) {
            float4 a = *(const float4*)&ztl[tid][0];
            float4 bq = *(const float4*)&ztl[tid][4];
            m_stat[(size_t)bt * 64 + tid] =
                0.125f * (a.x + a.y + a.z + a.w + bq.x + bq.y + bq.z + bq.w);
        }
        float4 acc = {0.f, 0.f, 0.f, 0.f};
        #pragma unroll 4
        for (int k = 0; k < 64; k++) {
            float c = Cl[k * 128 + n];
            float4 z4 = *(const float4*)&ztl[k][shh * 4];
            acc.x += c * z4.x; acc.y += c * z4.y; acc.z += c * z4.z; acc.w += c * z4.w;
        }
        float bcv = bc[n];
        float yv = y[(size_t)bt * 128 + n];
        int yi = (int)yv;
        float ga = (yi < 2) ? 0.f
                 : ((yi == 2) ? 0.6931471805599453f
                 : ((yi == 3) ? 1.791759469228055f : 3.1780538303479458f));
        float term = 0.f;
        {
            float lr;
            lr = acc.x + bcv; term += yv * lr - expf(lr) - ga;
            lr = acc.y + bcv; term += yv * lr - expf(lr) - ga;
            lr = acc.z + bcv; term += yv * lr - expf(lr) - ga;
            lr = acc.w + bcv; term += yv * lr - expf(lr) - ga;
        }
        #pragma unroll
        for (int off = 32; off; off >>= 1) term += __shfl_down(term, off);
        if ((tid & 63) == 0) red4[tid >> 6] = term;
        __syncthreads();
        if (tid == 0) ell[bt] = 0.125f * (red4[0] + red4[1] + red4[2] + red4[3]);
    }
}

// ---------------------------------------------------------------------------
// Kernel L: loss = mean_b sum_t (kl - ell)
// ---------------------------------------------------------------------------
__global__ __launch_bounds__(256) void kL(
        const float* __restrict__ klp, const float* __restrict__ ell,
        float* __restrict__ out0) {
    __shared__ float red4[4];
    const int tid = threadIdx.x;
    float acc = 0.f;
    for (int i = tid; i < B * T; i += 256) {
        acc += klp[i] + klp[B * T + i] - ell[i];
    }
    #pragma unroll
    for (int off = 32; off; off >>= 1) acc += __shfl_down(acc, off);
    if ((tid & 63) == 0) red4[tid >> 6] = acc;
    __syncthreads();
    if (tid == 0) out0[0] = (red4[0] + red4[1] + red4[2] + red4[3]) * (1.0f / B);
}

// ---------------------------------------------------------------------------
extern "C" void kernel_launch(void* const* d_in, const int* in_sizes, int n_in,
                              void* d_out, int out_size, void* d_ws, size_t ws_size,
                              hipStream_t stream) {
    const float* y      = (const float*)d_in[0];
    // d_in[1] = n_samples (known: 8)
    const float* W_be   = (const float*)d_in[2];
    const float* b_be   = (const float*)d_in[3];
    const float* W_ic   = (const float*)d_in[4];
    const float* b_ic   = (const float*)d_in[5];
    const float* W_le1  = (const float*)d_in[6];
    const float* b_le1  = (const float*)d_in[7];
    const float* W_le2  = (const float*)d_in[8];
    const float* b_le2  = (const float*)d_in[9];
    const float* W_dyn1 = (const float*)d_in[10];
    const float* b_dyn1 = (const float*)d_in[11];
    const float* W_dyn2 = (const float*)d_in[12];
    const float* b_dyn2 = (const float*)d_in[13];
    const float* C      = (const float*)d_in[14];
    const float* b_c    = (const float*)d_in[15];
    const float* log_Q  = (const float*)d_in[16];
    const float* m_0    = (const float*)d_in[17];
    const float* log_Q_0= (const float*)d_in[18];
    const float* eps0   = (const float*)d_in[19];
    const float* eps    = (const float*)d_in[20];

    float* out = (float*)d_out;
    float* zo  = out + 1;                                  // z: S*B*T*L
    float* ms  = out + 1 + (size_t)S * B * T * L;          // m_stat: B*T*L

    float* ws   = (float*)d_ws;
    float* A    = ws;                                      // B*T*128
    float* h0   = A + (size_t)B * T * 128;                 // B*128
    float* klp  = h0 + (size_t)B * 128;                    // 2*B*T
    float* ellw = klp + (size_t)2 * B * T;                 // B*T

    kA<<<2048, 256, 0, stream>>>(y, W_be, b_be, W_le1, b_le1, A, h0);
    kB<<<128, 128, 0, stream>>>(h0, W_ic, b_ic, m_0, log_Q_0, eps0, zo, klp);
    kC<<<256, 256, 0, stream>>>(A, W_le1, W_le2, b_le2, W_dyn1, b_dyn1,
                                W_dyn2, b_dyn2, log_Q, eps, zo, klp);
    kP<<<4096, 256, 0, stream>>>(zo, C, b_c, y, ms, ellw);
    kL<<<1, 256, 0, stream>>>(klp, ellw, out);
}

// Round 2
// 1193.334 us; speedup vs baseline: 1.0687x; 1.0687x over previous
//
#include <hip/hip_runtime.h>

// Problem constants
constexpr int S = 8, B = 128, T = 256, N = 128;
constexpr int L = 64, Hh = 128, Hd = 64, Hl = 128;

#define DEVFN __device__ __forceinline__

typedef float   f32x4_t __attribute__((ext_vector_type(4)));
typedef _Float16 f16x8_t __attribute__((ext_vector_type(8)));
typedef _Float16 f16x4_t __attribute__((ext_vector_type(4)));

DEVFN float softplus_f(float x) {
    return (x > 0.f) ? (x + log1pf(expf(-x))) : log1pf(expf(x));
}

DEVFN float fast_tanh(float x) {
    // tanh(x) = 1 - 2/(exp2(2x*log2e)+1); saturates correctly at +/-inf
    float ex = __builtin_exp2f(x * 2.885390081777927f);
    return 1.f - 2.f / (ex + 1.f);
}

// ---------------------------------------------------------------------------
// Kernel A: per (b,t) row:  h = tanh(y @ W_be + b_be);  A = h @ W1a + b_le1
// ---------------------------------------------------------------------------
__global__ __launch_bounds__(256) void kA(
        const float* __restrict__ y,
        const float* __restrict__ W_be, const float* __restrict__ b_be,
        const float* __restrict__ W_le1, const float* __restrict__ b_le1,
        float* __restrict__ A, float* __restrict__ h0) {
    __shared__ float Wb[128 * 128];
    __shared__ float Wa[128 * 128];
    __shared__ float yt[128][16];
    __shared__ float ht[128][16];
    __shared__ float bbe[128], ble1[128];

    const int tid = threadIdx.x;
    {
        const float4* s1 = (const float4*)W_be;
        const float4* s2 = (const float4*)W_le1;   // rows 0..127 = W1a
        float4* d1 = (float4*)Wb;
        float4* d2 = (float4*)Wa;
        for (int i = tid; i < 4096; i += 256) { d1[i] = s1[i]; d2[i] = s2[i]; }
    }
    if (tid < 128) { bbe[tid] = b_be[tid]; ble1[tid] = b_le1[tid]; }

    const int bt0 = blockIdx.x * 16;
    {
        const float4* ys = (const float4*)(y + (size_t)bt0 * 128);
        for (int q = tid; q < 512; q += 256) {
            float4 v = ys[q];
            int r = q >> 5, n4 = (q & 31) * 4;
            yt[n4 + 0][r] = v.x; yt[n4 + 1][r] = v.y;
            yt[n4 + 2][r] = v.z; yt[n4 + 3][r] = v.w;
        }
    }
    __syncthreads();

    const int j = tid & 127, rh = tid >> 7;
    float acc[8];

    #pragma unroll
    for (int s = 0; s < 8; s++) acc[s] = bbe[j];
    #pragma unroll 4
    for (int k = 0; k < 128; k++) {
        float w = Wb[k * 128 + j];
        float4 a0 = *(const float4*)&yt[k][rh * 8];
        float4 a1 = *(const float4*)&yt[k][rh * 8 + 4];
        acc[0] += w * a0.x; acc[1] += w * a0.y; acc[2] += w * a0.z; acc[3] += w * a0.w;
        acc[4] += w * a1.x; acc[5] += w * a1.y; acc[6] += w * a1.z; acc[7] += w * a1.w;
    }
    #pragma unroll
    for (int s = 0; s < 8; s++) ht[j][rh * 8 + s] = tanhf(acc[s]);
    __syncthreads();

    #pragma unroll
    for (int s = 0; s < 8; s++) acc[s] = ble1[j];
    #pragma unroll 4
    for (int k = 0; k < 128; k++) {
        float w = Wa[k * 128 + j];
        float4 a0 = *(const float4*)&ht[k][rh * 8];
        float4 a1 = *(const float4*)&ht[k][rh * 8 + 4];
        acc[0] += w * a0.x; acc[1] += w * a0.y; acc[2] += w * a0.z; acc[3] += w * a0.w;
        acc[4] += w * a1.x; acc[5] += w * a1.y; acc[6] += w * a1.z; acc[7] += w * a1.w;
    }
    #pragma unroll
    for (int s = 0; s < 8; s++) {
        int r = rh * 8 + s;
        A[(size_t)(bt0 + r) * 128 + j] = acc[s];
    }
    if (rh == 0 && (bt0 & 255) == 0) {
        h0[(bt0 >> 8) * 128 + j] = ht[j][0];
    }
}

// ---------------------------------------------------------------------------
// Kernel B: initial step (t=0)
// ---------------------------------------------------------------------------
__global__ __launch_bounds__(128) void kB(
        const float* __restrict__ h0, const float* __restrict__ W_ic,
        const float* __restrict__ b_ic, const float* __restrict__ m_0,
        const float* __restrict__ log_Q_0, const float* __restrict__ eps0,
        float* __restrict__ zout, float* __restrict__ klp) {
    __shared__ float hr[128];
    __shared__ float mp[128];
    const int b = blockIdx.x, tid = threadIdx.x;
    hr[tid] = h0[b * 128 + tid];
    __syncthreads();
    float acc = b_ic[tid];
    #pragma unroll 8
    for (int k = 0; k < 128; k++) acc += hr[k] * W_ic[k * 128 + tid];
    mp[tid] = acc;
    __syncthreads();

    float term = 0.f;
    if (tid < 64) {
        float m = mp[tid];
        float P = softplus_f(mp[tid + 64]);
        float sq = sqrtf(P);
        #pragma unroll
        for (int s = 0; s < 8; s++) {
            float e = eps0[((size_t)s * B + b) * 64 + tid];
            zout[(((size_t)s * B + b) * T + 0) * 64 + tid] = m + sq * e;
        }
        float Q0 = softplus_f(log_Q_0[tid]);
        float d = m - m_0[tid];
        term = 0.5f * (logf(Q0) - logf(P) + (P + d * d) / Q0 - 1.f);
    }
    #pragma unroll
    for (int off = 32; off; off >>= 1) term += __shfl_down(term, off);
    if (tid == 0) {
        klp[(size_t)b * T + 0] = term;
        klp[(size_t)B * T + (size_t)b * T + 0] = 0.f;
    }
}

// ---------------------------------------------------------------------------
// Kernel C (MFMA): sequential scan t=1..T-1.
// 256 blocks = (b, sample-half); 256 threads = 4 waves.
// Orientation: D = W^T-tile[16 outcols x 32k] * actT[32k x 16 samples(4 used)].
// Fragment convention (same bijection for A and B, HW pairs slots identically):
//   lane l: lo=l&15, hi=l>>4;  A[row=lo][k=k0+8*hi+e], B[k=k0+8*hi+e][col=lo]
//   D: col(sample)=lo, row(outcol offset)=4*hi+reg   [verified C/D layout]
// Weights live in per-lane VGPR fragments (loaded once). Activations stream
// through small padded LDS buffers as fp16.
// Wave w owns: hid cols [32w,32w+32); g/mu/m cols [16w,16w+16); P cols
// [64+16w, 64+16w+16)  -> m,P,mu for the same col live in the same lane.
// ---------------------------------------------------------------------------
__global__ __launch_bounds__(256, 1) void kC(
        const float* __restrict__ Aglob,
        const float* __restrict__ W_le1, const float* __restrict__ W_le2,
        const float* __restrict__ b_le2,
        const float* __restrict__ W_dyn1, const float* __restrict__ b_dyn1,
        const float* __restrict__ W_dyn2, const float* __restrict__ b_dyn2,
        const float* __restrict__ log_Q, const float* __restrict__ eps,
        float* __restrict__ zout, float* __restrict__ klp) {
    __shared__ alignas(16) _Float16 zSm[16][72];    // [sample][k] padded
    __shared__ alignas(16) _Float16 hidS[16][136];  // [sample][k] padded
    __shared__ alignas(16) _Float16 gS[16][72];
    __shared__ float red[16];                       // [wave][sample]

    const int tid = threadIdx.x;
    const int b = blockIdx.x >> 1, sh = blockIdx.x & 1, s0 = sh * 4;
    const int w = tid >> 6, l = tid & 63;
    const int lo = l & 15, hi = l >> 4;
    const bool sAct = (lo < 4);
    const int cg = 16 * w + 4 * hi;      // this lane's m/P/mu/g col base (+r)

    // ---- zero LDS (rows s>=4 stay zero forever) ----
    {
        _Float16* p1 = &zSm[0][0];
        _Float16* p2 = &hidS[0][0];
        _Float16* p3 = &gS[0][0];
        for (int i = tid; i < 16 * 72; i += 256) { p1[i] = (_Float16)0.f; p3[i] = (_Float16)0.f; }
        for (int i = tid; i < 16 * 136; i += 256) p2[i] = (_Float16)0.f;
    }

    // ---- load static weight fragments into VGPRs ----
    f16x8_t a1[2][2], a2[2][4], a3[2], a4[2];
    #pragma unroll
    for (int ct = 0; ct < 2; ++ct)
        #pragma unroll
        for (int kt = 0; kt < 2; ++kt) {
            f16x8_t f;
            #pragma unroll
            for (int e = 0; e < 8; ++e)
                f[e] = (_Float16)W_le1[(size_t)(128 + kt * 32 + 8 * hi + e) * 128 + (32 * w + 16 * ct + lo)];
            a1[ct][kt] = f;
        }
    #pragma unroll
    for (int ct = 0; ct < 2; ++ct) {
        const int col = (ct == 0 ? 16 * w : 64 + 16 * w) + lo;
        #pragma unroll
        for (int kt = 0; kt < 4; ++kt) {
            f16x8_t f;
            #pragma unroll
            for (int e = 0; e < 8; ++e)
                f[e] = (_Float16)W_le2[(size_t)(kt * 32 + 8 * hi + e) * 128 + col];
            a2[ct][kt] = f;
        }
    }
    #pragma unroll
    for (int kt = 0; kt < 2; ++kt) {
        f16x8_t f, g;
        #pragma unroll
        for (int e = 0; e < 8; ++e) {
            f[e] = (_Float16)W_dyn1[(size_t)(kt * 32 + 8 * hi + e) * 64 + (16 * w + lo)];
            g[e] = (_Float16)W_dyn2[(size_t)(kt * 32 + 8 * hi + e) * 64 + (16 * w + lo)];
        }
        a3[kt] = f; a4[kt] = g;
    }

    // ---- per-lane constants ----
    const f32x4_t bm  = *(const f32x4_t*)&b_le2[cg];
    const f32x4_t bp  = *(const f32x4_t*)&b_le2[64 + cg];
    const f32x4_t bmu = *(const f32x4_t*)&b_dyn2[cg];
    const f32x4_t bd1v= *(const f32x4_t*)&b_dyn1[cg];
    float Qr[4], lQr[4];
    #pragma unroll
    for (int r = 0; r < 4; ++r) {
        float q = softplus_f(log_Q[cg + r]);
        Qr[r] = q; lQr[r] = logf(q);
    }

    __syncthreads();
    // ---- stage z0 (fp32 global -> fp16 LDS), thread (s,l6) ----
    {
        int ss = tid >> 6, l6 = tid & 63;
        zSm[ss][l6] = (_Float16)zout[(((size_t)(s0 + ss) * B + b) * T + 0) * 64 + l6];
    }
    __syncthreads();

    for (int t = 1; t < T; ++t) {
        // global prefetch (hidden under MFMAs)
        const f32x4_t areg0 = *(const f32x4_t*)&Aglob[((size_t)b * T + t) * 128 + 32 * w + 4 * hi];
        const f32x4_t areg1 = *(const f32x4_t*)&Aglob[((size_t)b * T + t) * 128 + 32 * w + 16 + 4 * hi];
        f32x4_t epsv = {0.f, 0.f, 0.f, 0.f};
        if (sAct)
            epsv = *(const f32x4_t*)&eps[((((size_t)(t - 1) * S) + s0 + lo) * B + b) * 64 + cg];

        // ---- phase A: hid = tanh(A_t + z@W1b) ; g = tanh(z@Wd1 + bd1) ----
        const f16x8_t bz0 = *(const f16x8_t*)&zSm[lo][8 * hi];
        const f16x8_t bz1 = *(const f16x8_t*)&zSm[lo][32 + 8 * hi];

        f32x4_t acc1a = {0.f,0.f,0.f,0.f}, acc1b = {0.f,0.f,0.f,0.f}, acc3 = {0.f,0.f,0.f,0.f};
        acc1a = __builtin_amdgcn_mfma_f32_16x16x32_f16(a1[0][0], bz0, acc1a, 0, 0, 0);
        acc1b = __builtin_amdgcn_mfma_f32_16x16x32_f16(a1[1][0], bz0, acc1b, 0, 0, 0);
        acc3  = __builtin_amdgcn_mfma_f32_16x16x32_f16(a3[0],    bz0, acc3,  0, 0, 0);
        acc1a = __builtin_amdgcn_mfma_f32_16x16x32_f16(a1[0][1], bz1, acc1a, 0, 0, 0);
        acc1b = __builtin_amdgcn_mfma_f32_16x16x32_f16(a1[1][1], bz1, acc1b, 0, 0, 0);
        acc3  = __builtin_amdgcn_mfma_f32_16x16x32_f16(a3[1],    bz1, acc3,  0, 0, 0);

        if (sAct) {
            f16x4_t hv0, hv1, gv;
            #pragma unroll
            for (int r = 0; r < 4; ++r) {
                hv0[r] = (_Float16)fast_tanh(acc1a[r] + areg0[r]);
                hv1[r] = (_Float16)fast_tanh(acc1b[r] + areg1[r]);
                gv[r]  = (_Float16)fast_tanh(acc3[r] + bd1v[r]);
            }
            *(f16x4_t*)&hidS[lo][32 * w + 4 * hi]      = hv0;
            *(f16x4_t*)&hidS[lo][32 * w + 16 + 4 * hi] = hv1;
            *(f16x4_t*)&gS[lo][cg]                     = gv;
        }
        __syncthreads();   // (2) hid/g visible

        // ---- phase B: mp = hid@W2 + b2 ; mu = g@Wd2 + bd2 ----
        const f16x8_t bh0 = *(const f16x8_t*)&hidS[lo][ 0 + 8 * hi];
        const f16x8_t bh1 = *(const f16x8_t*)&hidS[lo][32 + 8 * hi];
        const f16x8_t bh2 = *(const f16x8_t*)&hidS[lo][64 + 8 * hi];
        const f16x8_t bh3 = *(const f16x8_t*)&hidS[lo][96 + 8 * hi];
        const f16x8_t bg0 = *(const f16x8_t*)&gS[lo][8 * hi];
        const f16x8_t bg1 = *(const f16x8_t*)&gS[lo][32 + 8 * hi];

        f32x4_t accm = {0.f,0.f,0.f,0.f}, accp = {0.f,0.f,0.f,0.f}, acc4 = {0.f,0.f,0.f,0.f};
        accm = __builtin_amdgcn_mfma_f32_16x16x32_f16(a2[0][0], bh0, accm, 0, 0, 0);
        accp = __builtin_amdgcn_mfma_f32_16x16x32_f16(a2[1][0], bh0, accp, 0, 0, 0);
        acc4 = __builtin_amdgcn_mfma_f32_16x16x32_f16(a4[0],    bg0, acc4, 0, 0, 0);
        accm = __builtin_amdgcn_mfma_f32_16x16x32_f16(a2[0][1], bh1, accm, 0, 0, 0);
        accp = __builtin_amdgcn_mfma_f32_16x16x32_f16(a2[1][1], bh1, accp, 0, 0, 0);
        acc4 = __builtin_amdgcn_mfma_f32_16x16x32_f16(a4[1],    bg1, acc4, 0, 0, 0);
        accm = __builtin_amdgcn_mfma_f32_16x16x32_f16(a2[0][2], bh2, accm, 0, 0, 0);
        accp = __builtin_amdgcn_mfma_f32_16x16x32_f16(a2[1][2], bh2, accp, 0, 0, 0);
        accm = __builtin_amdgcn_mfma_f32_16x16x32_f16(a2[0][3], bh3, accm, 0, 0, 0);
        accp = __builtin_amdgcn_mfma_f32_16x16x32_f16(a2[1][3], bh3, accp, 0, 0, 0);

        if (sAct) {
            float term = 0.f;
            f16x4_t zv;
            f32x4_t zst;
            #pragma unroll
            for (int r = 0; r < 4; ++r) {
                float m  = accm[r] + bm[r];
                float p2 = accp[r] + bp[r];
                float P  = softplus_f(p2);
                float mu = acc4[r] + bmu[r];
                float z  = m + sqrtf(P) * epsv[r];
                zst[r] = z;
                zv[r]  = (_Float16)z;
                float d = m - mu;
                term += lQr[r] - logf(P) + (P + d * d) / Qr[r] - 1.f;
            }
            term *= 0.5f;
            *(f32x4_t*)&zout[(((size_t)(s0 + lo) * B + b) * T + t) * 64 + cg] = zst;
            *(f16x4_t*)&zSm[lo][cg] = zv;
            term += __shfl_down(term, 32);
            term += __shfl_down(term, 16);
            if (l < 4) red[w * 4 + l] = term;
        }
        __syncthreads();   // (1) z / red visible

        if (tid < 16) {
            float v = red[tid];
            v += __shfl_down(v, 8);
            v += __shfl_down(v, 4);
            v += __shfl_down(v, 2);
            v += __shfl_down(v, 1);
            if (tid == 0)
                klp[(size_t)sh * B * T + (size_t)b * T + t] = 0.125f * v;
        }
    }
}

// ---------------------------------------------------------------------------
// Kernel P: projection + Poisson ell + m_stat.
// ---------------------------------------------------------------------------
__global__ __launch_bounds__(256) void kP(
        const float* __restrict__ zin, const float* __restrict__ C,
        const float* __restrict__ b_c, const float* __restrict__ y,
        float* __restrict__ m_stat, float* __restrict__ ell) {
    __shared__ float Cl[64 * 128];
    __shared__ float bc[128];
    __shared__ float ztl[64][8];
    __shared__ float red4[4];

    const int tid = threadIdx.x;
    {
        const float4* s = (const float4*)C;
        float4* d = (float4*)Cl;
        for (int i = tid; i < 2048; i += 256) d[i] = s[i];
    }
    if (tid < 128) bc[tid] = b_c[tid];

    const int bt0 = blockIdx.x * 8;
    const int n = tid & 127, shh = tid >> 7;

    for (int it = 0; it < 8; it++) {
        const int bt = bt0 + it;
        const int b = bt >> 8, t = bt & 255;
        __syncthreads();
        {
            int s_ = tid >> 6, l_ = tid & 63;
            ztl[l_][s_] = zin[(((size_t)s_ * B + b) * T + t) * 64 + l_];
            int i1 = tid + 256;
            s_ = i1 >> 6; l_ = i1 & 63;
            ztl[l_][s_] = zin[(((size_t)s_ * B + b) * T + t) * 64 + l_];
        }
        __syncthreads();
        if (tid < 64) {
            float4 a = *(const float4*)&ztl[tid][0];
            float4 bq = *(const float4*)&ztl[tid][4];
            m_stat[(size_t)bt * 64 + tid] =
                0.125f * (a.x + a.y + a.z + a.w + bq.x + bq.y + bq.z + bq.w);
        }
        float4 acc = {0.f, 0.f, 0.f, 0.f};
        #pragma unroll 4
        for (int k = 0; k < 64; k++) {
            float c = Cl[k * 128 + n];
            float4 z4 = *(const float4*)&ztl[k][shh * 4];
            acc.x += c * z4.x; acc.y += c * z4.y; acc.z += c * z4.z; acc.w += c * z4.w;
        }
        float bcv = bc[n];
        float yv = y[(size_t)bt * 128 + n];
        int yi = (int)yv;
        float ga = (yi < 2) ? 0.f
                 : ((yi == 2) ? 0.6931471805599453f
                 : ((yi == 3) ? 1.791759469228055f : 3.1780538303479458f));
        float term = 0.f;
        {
            float lr;
            lr = acc.x + bcv; term += yv * lr - expf(lr) - ga;
            lr = acc.y + bcv; term += yv * lr - expf(lr) - ga;
            lr = acc.z + bcv; term += yv * lr - expf(lr) - ga;
            lr = acc.w + bcv; term += yv * lr - expf(lr) - ga;
        }
        #pragma unroll
        for (int off = 32; off; off >>= 1) term += __shfl_down(term, off);
        if ((tid & 63) == 0) red4[tid >> 6] = term;
        __syncthreads();
        if (tid == 0) ell[bt] = 0.125f * (red4[0] + red4[1] + red4[2] + red4[3]);
    }
}

// ---------------------------------------------------------------------------
// Kernel L: loss = mean_b sum_t (kl - ell)
// ---------------------------------------------------------------------------
__global__ __launch_bounds__(256) void kL(
        const float* __restrict__ klp, const float* __restrict__ ell,
        float* __restrict__ out0) {
    __shared__ float red4[4];
    const int tid = threadIdx.x;
    float acc = 0.f;
    for (int i = tid; i < B * T; i += 256) {
        acc += klp[i] + klp[B * T + i] - ell[i];
    }
    #pragma unroll
    for (int off = 32; off; off >>= 1) acc += __shfl_down(acc, off);
    if ((tid & 63) == 0) red4[tid >> 6] = acc;
    __syncthreads();
    if (tid == 0) out0[0] = (red4[0] + red4[1] + red4[2] + red4[3]) * (1.0f / B);
}

// ---------------------------------------------------------------------------
extern "C" void kernel_launch(void* const* d_in, const int* in_sizes, int n_in,
                              void* d_out, int out_size, void* d_ws, size_t ws_size,
                              hipStream_t stream) {
    const float* y      = (const float*)d_in[0];
    const float* W_be   = (const float*)d_in[2];
    const float* b_be   = (const float*)d_in[3];
    const float* W_ic   = (const float*)d_in[4];
    const float* b_ic   = (const float*)d_in[5];
    const float* W_le1  = (const float*)d_in[6];
    const float* b_le1  = (const float*)d_in[7];
    const float* W_le2  = (const float*)d_in[8];
    const float* b_le2  = (const float*)d_in[9];
    const float* W_dyn1 = (const float*)d_in[10];
    const float* b_dyn1 = (const float*)d_in[11];
    const float* W_dyn2 = (const float*)d_in[12];
    const float* b_dyn2 = (const float*)d_in[13];
    const float* C      = (const float*)d_in[14];
    const float* b_c    = (const float*)d_in[15];
    const float* log_Q  = (const float*)d_in[16];
    const float* m_0    = (const float*)d_in[17];
    const float* log_Q_0= (const float*)d_in[18];
    const float* eps0   = (const float*)d_in[19];
    const float* eps    = (const float*)d_in[20];

    float* out = (float*)d_out;
    float* zo  = out + 1;
    float* ms  = out + 1 + (size_t)S * B * T * L;

    float* ws   = (float*)d_ws;
    float* A    = ws;                                      // B*T*128
    float* h0   = A + (size_t)B * T * 128;                 // B*128
    float* klp  = h0 + (size_t)B * 128;                    // 2*B*T
    float* ellw = klp + (size_t)2 * B * T;                 // B*T

    kA<<<2048, 256, 0, stream>>>(y, W_be, b_be, W_le1, b_le1, A, h0);
    kB<<<128, 128, 0, stream>>>(h0, W_ic, b_ic, m_0, log_Q_0, eps0, zo, klp);
    kC<<<256, 256, 0, stream>>>(A, W_le1, W_le2, b_le2, W_dyn1, b_dyn1,
                                W_dyn2, b_dyn2, log_Q, eps, zo, klp);
    kP<<<4096, 256, 0, stream>>>(zo, C, b_c, y, ms, ellw);
    kL<<<1, 256, 0, stream>>>(klp, ellw, out);
}

// Round 3
// 603.199 us; speedup vs baseline: 2.1143x; 1.9783x over previous
//
#include <hip/hip_runtime.h>

// Problem constants
constexpr int S = 8, B = 128, T = 256, N = 128;
constexpr int L = 64, Hh = 128, Hd = 64, Hl = 128;

#define DEVFN __device__ __forceinline__

typedef float    f32x4_t __attribute__((ext_vector_type(4)));
typedef _Float16 f16x8_t __attribute__((ext_vector_type(8)));
typedef _Float16 f16x4_t __attribute__((ext_vector_type(4)));

DEVFN float softplus_f(float x) {            // accurate (prologue only)
    return (x > 0.f) ? (x + log1pf(expf(-x))) : log1pf(expf(x));
}
DEVFN float softplus_fast(float x) {         // branchless, native trans
    return fmaxf(x, 0.f) + __logf(1.f + __expf(-fabsf(x)));
}
DEVFN float fast_tanh(float x) {
    float ex = __builtin_exp2f(x * 2.885390081777927f);
    return 1.f - 2.f / (ex + 1.f);
}

// ---------------------------------------------------------------------------
// Kernel A: per (b,t) row:  h = tanh(y @ W_be + b_be);  A = h @ W1a + b_le1
// ---------------------------------------------------------------------------
__global__ __launch_bounds__(256) void kA(
        const float* __restrict__ y,
        const float* __restrict__ W_be, const float* __restrict__ b_be,
        const float* __restrict__ W_le1, const float* __restrict__ b_le1,
        float* __restrict__ A, float* __restrict__ h0) {
    __shared__ float Wb[128 * 128];
    __shared__ float Wa[128 * 128];
    __shared__ float yt[128][16];
    __shared__ float ht[128][16];
    __shared__ float bbe[128], ble1[128];

    const int tid = threadIdx.x;
    {
        const float4* s1 = (const float4*)W_be;
        const float4* s2 = (const float4*)W_le1;   // rows 0..127 = W1a
        float4* d1 = (float4*)Wb;
        float4* d2 = (float4*)Wa;
        for (int i = tid; i < 4096; i += 256) { d1[i] = s1[i]; d2[i] = s2[i]; }
    }
    if (tid < 128) { bbe[tid] = b_be[tid]; ble1[tid] = b_le1[tid]; }

    const int bt0 = blockIdx.x * 16;
    {
        const float4* ys = (const float4*)(y + (size_t)bt0 * 128);
        for (int q = tid; q < 512; q += 256) {
            float4 v = ys[q];
            int r = q >> 5, n4 = (q & 31) * 4;
            yt[n4 + 0][r] = v.x; yt[n4 + 1][r] = v.y;
            yt[n4 + 2][r] = v.z; yt[n4 + 3][r] = v.w;
        }
    }
    __syncthreads();

    const int j = tid & 127, rh = tid >> 7;
    float acc[8];

    #pragma unroll
    for (int s = 0; s < 8; s++) acc[s] = bbe[j];
    #pragma unroll 4
    for (int k = 0; k < 128; k++) {
        float w = Wb[k * 128 + j];
        float4 a0 = *(const float4*)&yt[k][rh * 8];
        float4 a1 = *(const float4*)&yt[k][rh * 8 + 4];
        acc[0] += w * a0.x; acc[1] += w * a0.y; acc[2] += w * a0.z; acc[3] += w * a0.w;
        acc[4] += w * a1.x; acc[5] += w * a1.y; acc[6] += w * a1.z; acc[7] += w * a1.w;
    }
    #pragma unroll
    for (int s = 0; s < 8; s++) ht[j][rh * 8 + s] = tanhf(acc[s]);
    __syncthreads();

    #pragma unroll
    for (int s = 0; s < 8; s++) acc[s] = ble1[j];
    #pragma unroll 4
    for (int k = 0; k < 128; k++) {
        float w = Wa[k * 128 + j];
        float4 a0 = *(const float4*)&ht[k][rh * 8];
        float4 a1 = *(const float4*)&ht[k][rh * 8 + 4];
        acc[0] += w * a0.x; acc[1] += w * a0.y; acc[2] += w * a0.z; acc[3] += w * a0.w;
        acc[4] += w * a1.x; acc[5] += w * a1.y; acc[6] += w * a1.z; acc[7] += w * a1.w;
    }
    #pragma unroll
    for (int s = 0; s < 8; s++) {
        int r = rh * 8 + s;
        A[(size_t)(bt0 + r) * 128 + j] = acc[s];
    }
    if (rh == 0 && (bt0 & 255) == 0) {
        h0[(bt0 >> 8) * 128 + j] = ht[j][0];
    }
}

// ---------------------------------------------------------------------------
// Kernel B: initial step (t=0). Zeros all 4 kl slabs at t=0.
// ---------------------------------------------------------------------------
__global__ __launch_bounds__(128) void kB(
        const float* __restrict__ h0, const float* __restrict__ W_ic,
        const float* __restrict__ b_ic, const float* __restrict__ m_0,
        const float* __restrict__ log_Q_0, const float* __restrict__ eps0,
        float* __restrict__ zout, float* __restrict__ klp) {
    __shared__ float hr[128];
    __shared__ float mp[128];
    const int b = blockIdx.x, tid = threadIdx.x;
    hr[tid] = h0[b * 128 + tid];
    __syncthreads();
    float acc = b_ic[tid];
    #pragma unroll 8
    for (int k = 0; k < 128; k++) acc += hr[k] * W_ic[k * 128 + tid];
    mp[tid] = acc;
    __syncthreads();

    float term = 0.f;
    if (tid < 64) {
        float m = mp[tid];
        float P = softplus_f(mp[tid + 64]);
        float sq = sqrtf(P);
        #pragma unroll
        for (int s = 0; s < 8; s++) {
            float e = eps0[((size_t)s * B + b) * 64 + tid];
            zout[(((size_t)s * B + b) * T + 0) * 64 + tid] = m + sq * e;
        }
        float Q0 = softplus_f(log_Q_0[tid]);
        float d = m - m_0[tid];
        term = 0.5f * (logf(Q0) - logf(P) + (P + d * d) / Q0 - 1.f);
    }
    #pragma unroll
    for (int off = 32; off; off >>= 1) term += __shfl_down(term, off);
    if (tid == 0) {
        klp[(size_t)b * T + 0] = term;
        klp[(size_t)B * T + (size_t)b * T + 0] = 0.f;
        klp[(size_t)2 * B * T + (size_t)b * T + 0] = 0.f;
        klp[(size_t)3 * B * T + (size_t)b * T + 0] = 0.f;
    }
}

// ---------------------------------------------------------------------------
// Kernel C (MFMA, dense-lane epilogues): scan t=1..T-1.
// 512 blocks = (b, sample-quarter of 2); 256 threads = 4 waves; 2 blocks/CU.
// MFMA fragment convention as before (verified round 2):
//   lane l: lo=l&15, hi=l>>4; A[row=lo][k=8hi+e], B[k=8hi+e][col=lo]
//   D: col(sample)=lo, row(outcol offset)=4hi+reg
// Weights in per-lane VGPR fragments. Activations via f16 LDS; MFMA f32
// accumulators staged through f32 LDS so ALL lanes share activation/epilogue
// work (removes 4/16-lane serial chains).
// ---------------------------------------------------------------------------
__global__ __launch_bounds__(256, 1) void kC(
        const float* __restrict__ Aglob,
        const float* __restrict__ W_le1, const float* __restrict__ W_le2,
        const float* __restrict__ b_le2,
        const float* __restrict__ W_dyn1, const float* __restrict__ b_dyn1,
        const float* __restrict__ W_dyn2, const float* __restrict__ b_dyn2,
        const float* __restrict__ log_Q, const float* __restrict__ eps,
        float* __restrict__ zout, float* __restrict__ klp) {
    __shared__ alignas(16) _Float16 zSm[16][72];    // [sample][k]
    __shared__ alignas(16) _Float16 hidS[16][136];
    __shared__ alignas(16) _Float16 gS[16][72];
    __shared__ alignas(16) float stH[2][136];       // phase-A acc staging
    __shared__ alignas(16) float stG2[2][72];
    __shared__ alignas(16) float stM[2][136];       // phase-B acc staging
    __shared__ alignas(16) float stMU[2][72];
    __shared__ float red[4];

    const int tid = threadIdx.x;
    const int b = blockIdx.x >> 2, sq = blockIdx.x & 3, s0 = sq * 2;
    const int w = tid >> 6, l = tid & 63;
    const int lo = l & 15, hi = l >> 4;

    // ---- zero f16 LDS (rows s>=2 stay zero forever) ----
    {
        _Float16* p1 = &zSm[0][0];
        _Float16* p2 = &hidS[0][0];
        _Float16* p3 = &gS[0][0];
        for (int i = tid; i < 16 * 72; i += 256) { p1[i] = (_Float16)0.f; p3[i] = (_Float16)0.f; }
        for (int i = tid; i < 16 * 136; i += 256) p2[i] = (_Float16)0.f;
    }

    // ---- static weight fragments ----
    f16x8_t a1[2][2], a2[2][4], a3[2], a4[2];
    #pragma unroll
    for (int ct = 0; ct < 2; ++ct)
        #pragma unroll
        for (int kt = 0; kt < 2; ++kt) {
            f16x8_t f;
            #pragma unroll
            for (int e = 0; e < 8; ++e)
                f[e] = (_Float16)W_le1[(size_t)(128 + kt * 32 + 8 * hi + e) * 128 + (32 * w + 16 * ct + lo)];
            a1[ct][kt] = f;
        }
    #pragma unroll
    for (int ct = 0; ct < 2; ++ct) {
        const int col = (ct == 0 ? 16 * w : 64 + 16 * w) + lo;
        #pragma unroll
        for (int kt = 0; kt < 4; ++kt) {
            f16x8_t f;
            #pragma unroll
            for (int e = 0; e < 8; ++e)
                f[e] = (_Float16)W_le2[(size_t)(kt * 32 + 8 * hi + e) * 128 + col];
            a2[ct][kt] = f;
        }
    }
    #pragma unroll
    for (int kt = 0; kt < 2; ++kt) {
        f16x8_t f, g;
        #pragma unroll
        for (int e = 0; e < 8; ++e) {
            f[e] = (_Float16)W_dyn1[(size_t)(kt * 32 + 8 * hi + e) * 64 + (16 * w + lo)];
            g[e] = (_Float16)W_dyn2[(size_t)(kt * 32 + 8 * hi + e) * 64 + (16 * w + lo)];
        }
        a3[kt] = f; a4[kt] = g;
    }

    // ---- dense-thread constants ----
    // phase-A dense map: hid value (s = tid>>7, c = tid&127); g (tid<128: s=tid>>6, c=tid&63)
    const int hc = tid & 127, hs = tid >> 7;
    float bd1_c = (tid < 128) ? b_dyn1[tid & 63] : 0.f;
    // epilogue dense map: lanes l<32: v = w*32+l -> s=v>>6, c=v&63
    const int v = w * 32 + l;
    const int es = v >> 6, ec = v & 63;
    float bm_c = 0.f, bp_c = 0.f, bmu_c = 0.f, invQ_c = 0.f, lQ_c = 0.f;
    const float* epsp = nullptr;
    float* zp = nullptr;
    if (l < 32) {
        bm_c  = b_le2[ec];
        bp_c  = b_le2[64 + ec];
        bmu_c = b_dyn2[ec];
        float q = softplus_f(log_Q[ec]);
        invQ_c = 1.f / q; lQ_c = logf(q);
        epsp = eps + (((size_t)(s0 + es)) * B + b) * 64 + ec;          // t-1 = 0
        zp   = zout + ((((size_t)(s0 + es)) * B + b) * T + 1) * 64 + ec;
    }
    const float* ap = Aglob + ((size_t)b * T + 1) * 128 + hc;

    __syncthreads();
    // ---- stage z0 ----
    if (tid < 128) {
        int ss = tid >> 6, c6 = tid & 63;
        zSm[ss][c6] = (_Float16)zout[(((size_t)(s0 + ss) * B + b) * T + 0) * 64 + c6];
    }
    __syncthreads();

    for (int t = 1; t < T; ++t) {
        // prefetch this step's globals
        float a_pref = *ap; ap += 128;
        float e_pref = 0.f;
        if (l < 32) { e_pref = *epsp; epsp += (size_t)S * B * 64; }

        // ---- phase A MFMAs: z@W1b ; z@Wd1 ----
        const f16x8_t bz0 = *(const f16x8_t*)&zSm[lo][8 * hi];
        const f16x8_t bz1 = *(const f16x8_t*)&zSm[lo][32 + 8 * hi];

        f32x4_t acc1a = {0.f,0.f,0.f,0.f}, acc1b = {0.f,0.f,0.f,0.f}, acc3 = {0.f,0.f,0.f,0.f};
        acc1a = __builtin_amdgcn_mfma_f32_16x16x32_f16(a1[0][0], bz0, acc1a, 0, 0, 0);
        acc1b = __builtin_amdgcn_mfma_f32_16x16x32_f16(a1[1][0], bz0, acc1b, 0, 0, 0);
        acc3  = __builtin_amdgcn_mfma_f32_16x16x32_f16(a3[0],    bz0, acc3,  0, 0, 0);
        acc1a = __builtin_amdgcn_mfma_f32_16x16x32_f16(a1[0][1], bz1, acc1a, 0, 0, 0);
        acc1b = __builtin_amdgcn_mfma_f32_16x16x32_f16(a1[1][1], bz1, acc1b, 0, 0, 0);
        acc3  = __builtin_amdgcn_mfma_f32_16x16x32_f16(a3[1],    bz1, acc3,  0, 0, 0);

        if (lo < 2) {
            *(f32x4_t*)&stH[lo][32 * w + 4 * hi]      = acc1a;
            *(f32x4_t*)&stH[lo][32 * w + 16 + 4 * hi] = acc1b;
            *(f32x4_t*)&stG2[lo][16 * w + 4 * hi]     = acc3;
        }
        __syncthreads();   // (1) staging visible

        // ---- dense activation: all 256 threads ----
        {
            float hv = fast_tanh(stH[hs][hc] + a_pref);
            hidS[hs][hc] = (_Float16)hv;
            if (tid < 128) {
                float gv = fast_tanh(stG2[tid >> 6][tid & 63] + bd1_c);
                gS[tid >> 6][tid & 63] = (_Float16)gv;
            }
        }
        __syncthreads();   // (2) hid/g visible

        // ---- phase B MFMAs: hid@W2 ; g@Wd2 ----
        const f16x8_t bh0 = *(const f16x8_t*)&hidS[lo][ 0 + 8 * hi];
        const f16x8_t bh1 = *(const f16x8_t*)&hidS[lo][32 + 8 * hi];
        const f16x8_t bh2 = *(const f16x8_t*)&hidS[lo][64 + 8 * hi];
        const f16x8_t bh3 = *(const f16x8_t*)&hidS[lo][96 + 8 * hi];
        const f16x8_t bg0 = *(const f16x8_t*)&gS[lo][8 * hi];
        const f16x8_t bg1 = *(const f16x8_t*)&gS[lo][32 + 8 * hi];

        f32x4_t accm = {0.f,0.f,0.f,0.f}, accp = {0.f,0.f,0.f,0.f}, acc4 = {0.f,0.f,0.f,0.f};
        accm = __builtin_amdgcn_mfma_f32_16x16x32_f16(a2[0][0], bh0, accm, 0, 0, 0);
        accp = __builtin_amdgcn_mfma_f32_16x16x32_f16(a2[1][0], bh0, accp, 0, 0, 0);
        acc4 = __builtin_amdgcn_mfma_f32_16x16x32_f16(a4[0],    bg0, acc4, 0, 0, 0);
        accm = __builtin_amdgcn_mfma_f32_16x16x32_f16(a2[0][1], bh1, accm, 0, 0, 0);
        accp = __builtin_amdgcn_mfma_f32_16x16x32_f16(a2[1][1], bh1, accp, 0, 0, 0);
        acc4 = __builtin_amdgcn_mfma_f32_16x16x32_f16(a4[1],    bg1, acc4, 0, 0, 0);
        accm = __builtin_amdgcn_mfma_f32_16x16x32_f16(a2[0][2], bh2, accm, 0, 0, 0);
        accp = __builtin_amdgcn_mfma_f32_16x16x32_f16(a2[1][2], bh2, accp, 0, 0, 0);
        accm = __builtin_amdgcn_mfma_f32_16x16x32_f16(a2[0][3], bh3, accm, 0, 0, 0);
        accp = __builtin_amdgcn_mfma_f32_16x16x32_f16(a2[1][3], bh3, accp, 0, 0, 0);

        if (lo < 2) {
            *(f32x4_t*)&stM[lo][16 * w + 4 * hi]       = accm;
            *(f32x4_t*)&stM[lo][64 + 16 * w + 4 * hi]  = accp;
            *(f32x4_t*)&stMU[lo][16 * w + 4 * hi]      = acc4;
        }
        __syncthreads();   // (3) staging visible

        // ---- dense epilogue: lanes l<32 of each wave (128 values) ----
        float term = 0.f;
        if (l < 32) {
            float m  = stM[es][ec] + bm_c;
            float P  = softplus_fast(stM[es][64 + ec] + bp_c);
            float mu = stMU[es][ec] + bmu_c;
            float z  = m + sqrtf(P) * e_pref;
            *zp = z; zp += 64;
            zSm[es][ec] = (_Float16)z;
            float d = m - mu;
            term = lQ_c - __logf(P) + (P + d * d) * invQ_c - 1.f;
        }
        term += __shfl_down(term, 16);
        term += __shfl_down(term, 8);
        term += __shfl_down(term, 4);
        term += __shfl_down(term, 2);
        term += __shfl_down(term, 1);
        if (l == 0) red[w] = term;
        __syncthreads();   // (4) z / red visible
        if (tid == 0) {
            klp[(size_t)sq * B * T + (size_t)b * T + t] =
                0.0625f * (red[0] + red[1] + red[2] + red[3]);   // 0.5 * 1/8
        }
    }
}

// ---------------------------------------------------------------------------
// Kernel P: projection + Poisson ell + m_stat.
// ---------------------------------------------------------------------------
__global__ __launch_bounds__(256) void kP(
        const float* __restrict__ zin, const float* __restrict__ C,
        const float* __restrict__ b_c, const float* __restrict__ y,
        float* __restrict__ m_stat, float* __restrict__ ell) {
    __shared__ float Cl[64 * 128];
    __shared__ float bc[128];
    __shared__ float ztl[64][8];
    __shared__ float red4[4];

    const int tid = threadIdx.x;
    {
        const float4* s = (const float4*)C;
        float4* d = (float4*)Cl;
        for (int i = tid; i < 2048; i += 256) d[i] = s[i];
    }
    if (tid < 128) bc[tid] = b_c[tid];

    const int bt0 = blockIdx.x * 8;
    const int n = tid & 127, shh = tid >> 7;

    for (int it = 0; it < 8; it++) {
        const int bt = bt0 + it;
        const int b = bt >> 8, t = bt & 255;
        __syncthreads();
        {
            int s_ = tid >> 6, l_ = tid & 63;
            ztl[l_][s_] = zin[(((size_t)s_ * B + b) * T + t) * 64 + l_];
            int i1 = tid + 256;
            s_ = i1 >> 6; l_ = i1 & 63;
            ztl[l_][s_] = zin[(((size_t)s_ * B + b) * T + t) * 64 + l_];
        }
        __syncthreads();
        if (tid < 64) {
            float4 a = *(const float4*)&ztl[tid][0];
            float4 bq = *(const float4*)&ztl[tid][4];
            m_stat[(size_t)bt * 64 + tid] =
                0.125f * (a.x + a.y + a.z + a.w + bq.x + bq.y + bq.z + bq.w);
        }
        float4 acc = {0.f, 0.f, 0.f, 0.f};
        #pragma unroll 4
        for (int k = 0; k < 64; k++) {
            float c = Cl[k * 128 + n];
            float4 z4 = *(const float4*)&ztl[k][shh * 4];
            acc.x += c * z4.x; acc.y += c * z4.y; acc.z += c * z4.z; acc.w += c * z4.w;
        }
        float bcv = bc[n];
        float yv = y[(size_t)bt * 128 + n];
        int yi = (int)yv;
        float ga = (yi < 2) ? 0.f
                 : ((yi == 2) ? 0.6931471805599453f
                 : ((yi == 3) ? 1.791759469228055f : 3.1780538303479458f));
        float term = 0.f;
        {
            float lr;
            lr = acc.x + bcv; term += yv * lr - __expf(lr) - ga;
            lr = acc.y + bcv; term += yv * lr - __expf(lr) - ga;
            lr = acc.z + bcv; term += yv * lr - __expf(lr) - ga;
            lr = acc.w + bcv; term += yv * lr - __expf(lr) - ga;
        }
        #pragma unroll
        for (int off = 32; off; off >>= 1) term += __shfl_down(term, off);
        if ((tid & 63) == 0) red4[tid >> 6] = term;
        __syncthreads();
        if (tid == 0) ell[bt] = 0.125f * (red4[0] + red4[1] + red4[2] + red4[3]);
    }
}

// ---------------------------------------------------------------------------
// Kernel L: loss = mean_b sum_t (sum_sq kl_sq - ell)
// ---------------------------------------------------------------------------
__global__ __launch_bounds__(256) void kL(
        const float* __restrict__ klp, const float* __restrict__ ell,
        float* __restrict__ out0) {
    __shared__ float red4[4];
    const int tid = threadIdx.x;
    float acc = 0.f;
    for (int i = tid; i < B * T; i += 256) {
        acc += klp[i] + klp[B * T + i] + klp[2 * B * T + i] + klp[3 * B * T + i]
             - ell[i];
    }
    #pragma unroll
    for (int off = 32; off; off >>= 1) acc += __shfl_down(acc, off);
    if ((tid & 63) == 0) red4[tid >> 6] = acc;
    __syncthreads();
    if (tid == 0) out0[0] = (red4[0] + red4[1] + red4[2] + red4[3]) * (1.0f / B);
}

// ---------------------------------------------------------------------------
extern "C" void kernel_launch(void* const* d_in, const int* in_sizes, int n_in,
                              void* d_out, int out_size, void* d_ws, size_t ws_size,
                              hipStream_t stream) {
    const float* y      = (const float*)d_in[0];
    const float* W_be   = (const float*)d_in[2];
    const float* b_be   = (const float*)d_in[3];
    const float* W_ic   = (const float*)d_in[4];
    const float* b_ic   = (const float*)d_in[5];
    const float* W_le1  = (const float*)d_in[6];
    const float* b_le1  = (const float*)d_in[7];
    const float* W_le2  = (const float*)d_in[8];
    const float* b_le2  = (const float*)d_in[9];
    const float* W_dyn1 = (const float*)d_in[10];
    const float* b_dyn1 = (const float*)d_in[11];
    const float* W_dyn2 = (const float*)d_in[12];
    const float* b_dyn2 = (const float*)d_in[13];
    const float* C      = (const float*)d_in[14];
    const float* b_c    = (const float*)d_in[15];
    const float* log_Q  = (const float*)d_in[16];
    const float* m_0    = (const float*)d_in[17];
    const float* log_Q_0= (const float*)d_in[18];
    const float* eps0   = (const float*)d_in[19];
    const float* eps    = (const float*)d_in[20];

    float* out = (float*)d_out;
    float* zo  = out + 1;
    float* ms  = out + 1 + (size_t)S * B * T * L;

    float* ws   = (float*)d_ws;
    float* klp  = ws;                                      // 4*B*T
    float* ellw = klp + (size_t)4 * B * T;                 // B*T
    float* h0   = ellw + (size_t)B * T;                    // B*128
    float* A    = h0 + (size_t)B * 128;                    // B*T*128

    kA<<<2048, 256, 0, stream>>>(y, W_be, b_be, W_le1, b_le1, A, h0);
    kB<<<128, 128, 0, stream>>>(h0, W_ic, b_ic, m_0, log_Q_0, eps0, zo, klp);
    kC<<<512, 256, 0, stream>>>(A, W_le1, W_le2, b_le2, W_dyn1, b_dyn1,
                                W_dyn2, b_dyn2, log_Q, eps, zo, klp);
    kP<<<4096, 256, 0, stream>>>(zo, C, b_c, y, ms, ellw);
    kL<<<1, 256, 0, stream>>>(klp, ellw, out);
}